// Round 9
// baseline (273.189 us; speedup 1.0000x reference)
//
#include <hip/hip_runtime.h>
#include <hip/hip_bf16.h>

// out = A @ b, A sparse COO (rows, cols, vals), N=50000, E=1.6M, D=128, fp32.
// Round 9: 8 XCD-private slot copies, one 64B line per (row,copy).
//   scatter_x: block bid (XCD bid&7) reads its chunk ONCE (int4, 4 edges/thr),
//              appends packed (col<<16|bf16(val)) into copy bid&7. Per-copy
//              degree ~Poisson(4); CSX=16 x 4B = exactly one line per cell.
//   reduce_x : per row, stage all 8 copies' words into per-wave LDS (phase A),
//              then unified 16-deep unrolled bf16 gather loop (phase B).
//   memset -> cvt(b->bf16) -> scatter_x -> reduce_x -> spill_apply

#define D_DIM 128
#define CSX   16             // slots per (row, xcd-copy); Poisson(4) tail -> spill
#define SPILL_CAP (1 << 16)

__device__ inline uint f32_to_bf16(float f) {
    uint u = __float_as_uint(f);
    return (u + 0x7fffu + ((u >> 16) & 1u)) >> 16;   // RNE
}

// ---------------- b -> bf16 (RNE) ----------------
__global__ __launch_bounds__(256) void cvt_kernel(const float* __restrict__ b,
                                                  ushort* __restrict__ b16, int n8) {
    int i = blockIdx.x * 256 + threadIdx.x;
    int stride = gridDim.x * 256;
    for (; i < n8; i += stride) {
        float4 f0 = *reinterpret_cast<const float4*>(b + (size_t)i * 8);
        float4 f1 = *reinterpret_cast<const float4*>(b + (size_t)i * 8 + 4);
        uint r[8] = {f32_to_bf16(f0.x), f32_to_bf16(f0.y),
                     f32_to_bf16(f0.z), f32_to_bf16(f0.w),
                     f32_to_bf16(f1.x), f32_to_bf16(f1.y),
                     f32_to_bf16(f1.z), f32_to_bf16(f1.w)};
        uint4 w;
        w.x = r[0] | (r[1] << 16);
        w.y = r[2] | (r[3] << 16);
        w.z = r[4] | (r[5] << 16);
        w.w = r[6] | (r[7] << 16);
        *reinterpret_cast<uint4*>(b16 + (size_t)i * 8) = w;
    }
}

// ---------------- scatter into XCD-private slot copies ----------------
__global__ __launch_bounds__(256) void scatter_x(const int* __restrict__ rows,
                                                 const int* __restrict__ cols,
                                                 const float* __restrict__ vals,
                                                 int* __restrict__ rowcnt,
                                                 int* __restrict__ spill_cnt,
                                                 int2* __restrict__ spill,
                                                 uint* __restrict__ slots,
                                                 int E, int N) {
    const int  t = threadIdx.x;
    const int  x = blockIdx.x & 7;                 // XCD guess; correctness-free
    int*  cntx  = rowcnt + (size_t)x * N;
    uint* slotx = slots + (size_t)x * N * CSX;
    long e0 = (long)blockIdx.x * 1024 + t * 4;
    if (e0 + 3 < E) {
        int4   r4 = *reinterpret_cast<const int4*>(rows + e0);
        int4   c4 = *reinterpret_cast<const int4*>(cols + e0);
        float4 v4 = *reinterpret_cast<const float4*>(vals + e0);
        int   rr[4] = {r4.x, r4.y, r4.z, r4.w};
        int   cc[4] = {c4.x, c4.y, c4.z, c4.w};
        float vv[4] = {v4.x, v4.y, v4.z, v4.w};
        #pragma unroll
        for (int k = 0; k < 4; ++k) {
            int pos = atomicAdd(&cntx[rr[k]], 1);
            uint w  = ((uint)cc[k] << 16) | f32_to_bf16(vv[k]);
            if (pos < CSX) {
                slotx[(size_t)rr[k] * CSX + pos] = w;
            } else {
                int sp = atomicAdd(spill_cnt, 1);
                if (sp < SPILL_CAP)
                    spill[sp] = make_int2((rr[k] << 16) | cc[k], __float_as_int(vv[k]));
            }
        }
    } else {
        for (int k = 0; k < 4; ++k) {
            long e = e0 + k;
            if (e >= E) break;
            int r = rows[e], c = cols[e];
            float v = vals[e];
            int pos = atomicAdd(&cntx[r], 1);
            uint w  = ((uint)c << 16) | f32_to_bf16(v);
            if (pos < CSX) {
                slotx[(size_t)r * CSX + pos] = w;
            } else {
                int sp = atomicAdd(spill_cnt, 1);
                if (sp < SPILL_CAP)
                    spill[sp] = make_int2((r << 16) | c, __float_as_int(v));
            }
        }
    }
}

// ---------------- reduce: LDS-staged unified edge stream, bf16 gather ----------
__device__ inline void bf16_fma4(float4& acc, float v, uint2 u) {
    float f0 = __uint_as_float(u.x << 16);
    float f1 = __uint_as_float(u.x & 0xffff0000u);
    float f2 = __uint_as_float(u.y << 16);
    float f3 = __uint_as_float(u.y & 0xffff0000u);
    acc.x = fmaf(v, f0, acc.x);
    acc.y = fmaf(v, f1, acc.y);
    acc.z = fmaf(v, f2, acc.z);
    acc.w = fmaf(v, f3, acc.w);
}

__global__ __launch_bounds__(256) void reduce_x(const int* __restrict__ rowcnt,
                                                const uint* __restrict__ slots,
                                                const ushort* __restrict__ b16,
                                                float* __restrict__ out, int N) {
    __shared__ uint sbuf[4][8 * CSX];
    const int w    = threadIdx.x >> 6;
    const int lane = threadIdx.x & 63;
    const int half = lane >> 5;
    const int l32  = lane & 31;
    const int row  = blockIdx.x * 4 + w;
    if (row >= N) return;

    // phase A: stage all copies' slot words for this row into LDS (wave-local)
    int tot = 0;
    #pragma unroll
    for (int x = 0; x < 8; ++x) {
        int cx = __builtin_amdgcn_readfirstlane(rowcnt[(size_t)x * N + row]);
        if (cx > CSX) cx = CSX;
        if (lane < cx)
            sbuf[w][tot + lane] = slots[((size_t)x * N + row) * CSX + lane];
        tot += cx;
    }

    // phase B: unified gather loop (paired half-wave, 16 edges in flight)
    const ushort* bl = b16 + l32 * 4;
    float4 acc = make_float4(0.f, 0.f, 0.f, 0.f);
    int j = 0;
    for (; j + 16 <= tot; j += 16) {
        uint uu[8];
        #pragma unroll
        for (int k = 0; k < 8; ++k) uu[k] = sbuf[w][j + 2 * k + half];
        uint2 bv[8];
        #pragma unroll
        for (int k = 0; k < 8; ++k)
            bv[k] = *reinterpret_cast<const uint2*>(bl + (size_t)(uu[k] >> 16) * D_DIM);
        #pragma unroll
        for (int k = 0; k < 8; ++k)
            bf16_fma4(acc, __uint_as_float(uu[k] << 16), bv[k]);
    }
    for (; j + 4 <= tot; j += 4) {
        uint u0 = sbuf[w][j + half];
        uint u1 = sbuf[w][j + 2 + half];
        uint2 b0 = *reinterpret_cast<const uint2*>(bl + (size_t)(u0 >> 16) * D_DIM);
        uint2 b1 = *reinterpret_cast<const uint2*>(bl + (size_t)(u1 >> 16) * D_DIM);
        bf16_fma4(acc, __uint_as_float(u0 << 16), b0);
        bf16_fma4(acc, __uint_as_float(u1 << 16), b1);
    }
    for (; j + 2 <= tot; j += 2) {
        uint u = sbuf[w][j + half];
        uint2 bb = *reinterpret_cast<const uint2*>(bl + (size_t)(u >> 16) * D_DIM);
        bf16_fma4(acc, __uint_as_float(u << 16), bb);
    }
    if (j < tot) {                         // odd edge: half 1 contributes 0
        uint u = sbuf[w][j];
        uint  c = half ? 0u : (u >> 16);
        float v = half ? 0.f : __uint_as_float(u << 16);
        uint2 bb = *reinterpret_cast<const uint2*>(bl + (size_t)c * D_DIM);
        bf16_fma4(acc, v, bb);
    }
    acc.x += __shfl_xor(acc.x, 32, 64);
    acc.y += __shfl_xor(acc.y, 32, 64);
    acc.z += __shfl_xor(acc.z, 32, 64);
    acc.w += __shfl_xor(acc.w, 32, 64);
    if (half == 0)
        *reinterpret_cast<float4*>(out + (size_t)row * D_DIM + l32 * 4) = acc;
}

// ---------------- spill apply (after reduce): fp32 atomics ----------------
__global__ __launch_bounds__(256) void spill_apply(const int2* __restrict__ spill,
                                                   const int* __restrict__ spill_cnt,
                                                   const float* __restrict__ b,
                                                   float* __restrict__ out) {
    int total = *spill_cnt;
    if (total > SPILL_CAP) total = SPILL_CAP;
    const int lane  = threadIdx.x & 63;
    const int wid   = (blockIdx.x * 256 + threadIdx.x) >> 6;
    const int nwave = (gridDim.x * 256) >> 6;
    for (int i = wid; i < total; i += nwave) {
        int2 a = spill[i];
        int r = (int)((unsigned)a.x >> 16);
        int c = a.x & 0xffff;
        float v = __int_as_float(a.y);
        float2 bb = *reinterpret_cast<const float2*>(b + (size_t)c * D_DIM + lane * 2);
        atomicAdd(&out[(size_t)r * D_DIM + lane * 2],     v * bb.x);
        atomicAdd(&out[(size_t)r * D_DIM + lane * 2 + 1], v * bb.y);
    }
}

// ---------------- fallback: zero + pure atomic scatter ----------------
__global__ __launch_bounds__(256) void zero_kernel(float* __restrict__ out, size_t n4) {
    size_t i = (size_t)blockIdx.x * 256 + threadIdx.x;
    size_t stride = (size_t)gridDim.x * 256;
    for (; i < n4; i += stride)
        reinterpret_cast<float4*>(out)[i] = make_float4(0.f, 0.f, 0.f, 0.f);
}

__global__ __launch_bounds__(256) void atomic_spmm_kernel(const int* __restrict__ rows,
                                                          const int* __restrict__ cols,
                                                          const float* __restrict__ vals,
                                                          const float* __restrict__ b,
                                                          float* __restrict__ out, int E) {
    long long t = (long long)blockIdx.x * 256 + threadIdx.x;
    int e = (int)(t >> 5);
    int q = (int)(t & 31);
    if (e >= E) return;
    int   r = rows[e];
    int   c = cols[e];
    float v = vals[e];
    float4 bb = *reinterpret_cast<const float4*>(b + (size_t)c * D_DIM + q * 4);
    float* o = out + (size_t)r * D_DIM + q * 4;
    atomicAdd(o + 0, v * bb.x);
    atomicAdd(o + 1, v * bb.y);
    atomicAdd(o + 2, v * bb.z);
    atomicAdd(o + 3, v * bb.w);
}

extern "C" void kernel_launch(void* const* d_in, const int* in_sizes, int n_in,
                              void* d_out, int out_size, void* d_ws, size_t ws_size,
                              hipStream_t stream) {
    const int*   idx  = (const int*)d_in[0];   // [2, E] flat int32
    const float* vals = (const float*)d_in[1]; // [E]
    const float* b    = (const float*)d_in[3]; // [N, 128]
    float*       out  = (float*)d_out;

    const int E = in_sizes[1];
    const int N = in_sizes[3] / D_DIM;
    const int* rows = idx;
    const int* cols = idx + E;

    // ws: rowcnt[8N] | spill_cnt[1] | pad | spill[SPILL_CAP] int2
    //     | slots[8*N*CSX] uint | b16[N*128] ushort
    size_t spill_off = (((size_t)(8 * (size_t)N + 1) * sizeof(int)) + 15) & ~(size_t)15;
    size_t slots_off = spill_off + (size_t)SPILL_CAP * sizeof(int2);
    size_t b16_off   = slots_off + 8 * (size_t)N * CSX * sizeof(uint);
    size_t need      = b16_off + (size_t)N * D_DIM * sizeof(ushort);

    if (ws_size >= need && N <= 65536) {
        char*   ws        = (char*)d_ws;
        int*    rowcnt    = (int*)ws;
        int*    spill_cnt = rowcnt + 8 * (size_t)N;
        int2*   spill     = (int2*)(ws + spill_off);
        uint*   slots     = (uint*)(ws + slots_off);
        ushort* b16       = (ushort*)(ws + b16_off);

        hipMemsetAsync(rowcnt, 0, (8 * (size_t)N + 1) * sizeof(int), stream);
        cvt_kernel<<<2048, 256, 0, stream>>>(b, b16, N * D_DIM / 8);
        int sb = (int)((E + 1023) / 1024);
        scatter_x<<<sb, 256, 0, stream>>>(rows, cols, vals, rowcnt,
                                          spill_cnt, spill, slots, E, N);
        reduce_x<<<(N + 3) / 4, 256, 0, stream>>>(rowcnt, slots, b16, out, N);
        spill_apply<<<64, 256, 0, stream>>>(spill, spill_cnt, b, out);
    } else {
        size_t n4 = (size_t)N * D_DIM / 4;
        zero_kernel<<<2048, 256, 0, stream>>>(out, n4);
        long long total = (long long)E * 32;
        int ab = (int)((total + 255) / 256);
        atomic_spmm_kernel<<<ab, 256, 0, stream>>>(rows, cols, vals, b, out, E);
    }
}

// Round 11
// 270.994 us; speedup vs baseline: 1.0081x; 1.0081x over previous
//
#include <hip/hip_runtime.h>
#include <hip/hip_bf16.h>

// out = A @ b, A sparse COO (rows, cols, vals), N=50000, E=1.6M, D=128, fp32.
// Round 10b (compile fix): XCD-private slot copies keyed by the REAL XCC_ID
// (s_getreg), non-temporal input streaming via ext_vector types, cvt fused
// into the scatter launch.
//   memset(rowcnt) -> fused{cvt(b->bf16) | scatter_xcc} -> reduce_x -> spill
// Each (row, xcd-copy) cell = CSX(16) x 4B = exactly one 64B line, touched by
// one XCD's L2 only -> written back once.

#define D_DIM 128
#define CSX   16             // slots per (row, xcd-copy); Binom(deg,1/8) tail -> spill
#define SPILL_CAP (1 << 16)
#define CVTB  512            // blocks devoted to cvt inside the fused kernel

typedef int   vint4   __attribute__((ext_vector_type(4)));
typedef float vfloat4 __attribute__((ext_vector_type(4)));

__device__ inline uint f32_to_bf16(float f) {
    uint u = __float_as_uint(f);
    return (u + 0x7fffu + ((u >> 16) & 1u)) >> 16;   // RNE
}

__device__ inline int xcc_id() {
    int x;
    asm volatile("s_getreg_b32 %0, hwreg(HW_REG_XCC_ID)" : "=s"(x));
    return x & 7;
}

// ---------------- fused: cvt section + XCC-private slot scatter ----------------
__global__ __launch_bounds__(256) void cvt_scatter(const int* __restrict__ rows,
                                                   const int* __restrict__ cols,
                                                   const float* __restrict__ vals,
                                                   const float* __restrict__ b,
                                                   ushort* __restrict__ b16, int n8,
                                                   int* __restrict__ rowcnt,
                                                   int* __restrict__ spill_cnt,
                                                   int2* __restrict__ spill,
                                                   uint* __restrict__ slots,
                                                   int E, int N, int SB) {
    const int t = threadIdx.x;
    if ((int)blockIdx.x >= SB) {
        // ---- cvt: b (fp32) -> b16 (bf16), grid-stride over n8 groups of 8 ----
        int i = ((int)blockIdx.x - SB) * 256 + t;
        const int stride = CVTB * 256;
        for (; i < n8; i += stride) {
            float4 f0 = *reinterpret_cast<const float4*>(b + (size_t)i * 8);
            float4 f1 = *reinterpret_cast<const float4*>(b + (size_t)i * 8 + 4);
            uint r[8] = {f32_to_bf16(f0.x), f32_to_bf16(f0.y),
                         f32_to_bf16(f0.z), f32_to_bf16(f0.w),
                         f32_to_bf16(f1.x), f32_to_bf16(f1.y),
                         f32_to_bf16(f1.z), f32_to_bf16(f1.w)};
            uint4 w;
            w.x = r[0] | (r[1] << 16);
            w.y = r[2] | (r[3] << 16);
            w.z = r[4] | (r[5] << 16);
            w.w = r[6] | (r[7] << 16);
            *reinterpret_cast<uint4*>(b16 + (size_t)i * 8) = w;
        }
        return;
    }

    // ---- scatter: append edges into THIS XCD's private copy ----
    const int x = xcc_id();
    int*  cntx  = rowcnt + (size_t)x * N;
    uint* slotx = slots + (size_t)x * N * CSX;
    long e0 = (long)blockIdx.x * 1024 + t * 4;
    if (e0 + 3 < E) {
        vint4   r4 = __builtin_nontemporal_load(
                         reinterpret_cast<const vint4*>(rows + e0));
        vint4   c4 = __builtin_nontemporal_load(
                         reinterpret_cast<const vint4*>(cols + e0));
        vfloat4 v4 = __builtin_nontemporal_load(
                         reinterpret_cast<const vfloat4*>(vals + e0));
        int   rr[4] = {r4.x, r4.y, r4.z, r4.w};
        int   cc[4] = {c4.x, c4.y, c4.z, c4.w};
        float vv[4] = {v4.x, v4.y, v4.z, v4.w};
        #pragma unroll
        for (int k = 0; k < 4; ++k) {
            int pos = atomicAdd(&cntx[rr[k]], 1);
            uint w  = ((uint)cc[k] << 16) | f32_to_bf16(vv[k]);
            if (pos < CSX) {
                slotx[(size_t)rr[k] * CSX + pos] = w;
            } else {
                int sp = atomicAdd(spill_cnt, 1);
                if (sp < SPILL_CAP)
                    spill[sp] = make_int2((rr[k] << 16) | cc[k], __float_as_int(vv[k]));
            }
        }
    } else {
        for (int k = 0; k < 4; ++k) {
            long e = e0 + k;
            if (e >= E) break;
            int r = rows[e], c = cols[e];
            float v = vals[e];
            int pos = atomicAdd(&cntx[r], 1);
            uint w  = ((uint)c << 16) | f32_to_bf16(v);
            if (pos < CSX) {
                slotx[(size_t)r * CSX + pos] = w;
            } else {
                int sp = atomicAdd(spill_cnt, 1);
                if (sp < SPILL_CAP)
                    spill[sp] = make_int2((r << 16) | c, __float_as_int(v));
            }
        }
    }
}

// ---------------- reduce: LDS-staged unified edge stream, bf16 gather ----------
__device__ inline void bf16_fma4(float4& acc, float v, uint2 u) {
    float f0 = __uint_as_float(u.x << 16);
    float f1 = __uint_as_float(u.x & 0xffff0000u);
    float f2 = __uint_as_float(u.y << 16);
    float f3 = __uint_as_float(u.y & 0xffff0000u);
    acc.x = fmaf(v, f0, acc.x);
    acc.y = fmaf(v, f1, acc.y);
    acc.z = fmaf(v, f2, acc.z);
    acc.w = fmaf(v, f3, acc.w);
}

__global__ __launch_bounds__(256) void reduce_x(const int* __restrict__ rowcnt,
                                                const uint* __restrict__ slots,
                                                const ushort* __restrict__ b16,
                                                float* __restrict__ out, int N) {
    __shared__ uint sbuf[4][8 * CSX];
    const int w    = threadIdx.x >> 6;
    const int lane = threadIdx.x & 63;
    const int half = lane >> 5;
    const int l32  = lane & 31;
    const int row  = blockIdx.x * 4 + w;
    if (row >= N) return;

    // phase A: stage all copies' slot words for this row into LDS (wave-local)
    int tot = 0;
    #pragma unroll
    for (int x = 0; x < 8; ++x) {
        int cx = __builtin_amdgcn_readfirstlane(rowcnt[(size_t)x * N + row]);
        if (cx > CSX) cx = CSX;
        if (lane < cx)
            sbuf[w][tot + lane] = slots[((size_t)x * N + row) * CSX + lane];
        tot += cx;
    }

    // phase B: unified gather loop (paired half-wave, 16 edges in flight)
    const ushort* bl = b16 + l32 * 4;
    float4 acc = make_float4(0.f, 0.f, 0.f, 0.f);
    int j = 0;
    for (; j + 16 <= tot; j += 16) {
        uint uu[8];
        #pragma unroll
        for (int k = 0; k < 8; ++k) uu[k] = sbuf[w][j + 2 * k + half];
        uint2 bv[8];
        #pragma unroll
        for (int k = 0; k < 8; ++k)
            bv[k] = *reinterpret_cast<const uint2*>(bl + (size_t)(uu[k] >> 16) * D_DIM);
        #pragma unroll
        for (int k = 0; k < 8; ++k)
            bf16_fma4(acc, __uint_as_float(uu[k] << 16), bv[k]);
    }
    for (; j + 4 <= tot; j += 4) {
        uint u0 = sbuf[w][j + half];
        uint u1 = sbuf[w][j + 2 + half];
        uint2 b0 = *reinterpret_cast<const uint2*>(bl + (size_t)(u0 >> 16) * D_DIM);
        uint2 b1 = *reinterpret_cast<const uint2*>(bl + (size_t)(u1 >> 16) * D_DIM);
        bf16_fma4(acc, __uint_as_float(u0 << 16), b0);
        bf16_fma4(acc, __uint_as_float(u1 << 16), b1);
    }
    for (; j + 2 <= tot; j += 2) {
        uint u = sbuf[w][j + half];
        uint2 bb = *reinterpret_cast<const uint2*>(bl + (size_t)(u >> 16) * D_DIM);
        bf16_fma4(acc, __uint_as_float(u << 16), bb);
    }
    if (j < tot) {                         // odd edge: half 1 contributes 0
        uint u = sbuf[w][j];
        uint  c = half ? 0u : (u >> 16);
        float v = half ? 0.f : __uint_as_float(u << 16);
        uint2 bb = *reinterpret_cast<const uint2*>(bl + (size_t)c * D_DIM);
        bf16_fma4(acc, v, bb);
    }
    acc.x += __shfl_xor(acc.x, 32, 64);
    acc.y += __shfl_xor(acc.y, 32, 64);
    acc.z += __shfl_xor(acc.z, 32, 64);
    acc.w += __shfl_xor(acc.w, 32, 64);
    if (half == 0)
        *reinterpret_cast<float4*>(out + (size_t)row * D_DIM + l32 * 4) = acc;
}

// ---------------- spill apply (after reduce): fp32 atomics ----------------
__global__ __launch_bounds__(256) void spill_apply(const int2* __restrict__ spill,
                                                   const int* __restrict__ spill_cnt,
                                                   const float* __restrict__ b,
                                                   float* __restrict__ out) {
    int total = *spill_cnt;
    if (total > SPILL_CAP) total = SPILL_CAP;
    const int lane  = threadIdx.x & 63;
    const int wid   = (blockIdx.x * 256 + threadIdx.x) >> 6;
    const int nwave = (gridDim.x * 256) >> 6;
    for (int i = wid; i < total; i += nwave) {
        int2 a = spill[i];
        int r = (int)((unsigned)a.x >> 16);
        int c = a.x & 0xffff;
        float v = __int_as_float(a.y);
        float2 bb = *reinterpret_cast<const float2*>(b + (size_t)c * D_DIM + lane * 2);
        atomicAdd(&out[(size_t)r * D_DIM + lane * 2],     v * bb.x);
        atomicAdd(&out[(size_t)r * D_DIM + lane * 2 + 1], v * bb.y);
    }
}

// ---------------- fallback: zero + pure atomic scatter ----------------
__global__ __launch_bounds__(256) void zero_kernel(float* __restrict__ out, size_t n4) {
    size_t i = (size_t)blockIdx.x * 256 + threadIdx.x;
    size_t stride = (size_t)gridDim.x * 256;
    for (; i < n4; i += stride)
        reinterpret_cast<float4*>(out)[i] = make_float4(0.f, 0.f, 0.f, 0.f);
}

__global__ __launch_bounds__(256) void atomic_spmm_kernel(const int* __restrict__ rows,
                                                          const int* __restrict__ cols,
                                                          const float* __restrict__ vals,
                                                          const float* __restrict__ b,
                                                          float* __restrict__ out, int E) {
    long long t = (long long)blockIdx.x * 256 + threadIdx.x;
    int e = (int)(t >> 5);
    int q = (int)(t & 31);
    if (e >= E) return;
    int   r = rows[e];
    int   c = cols[e];
    float v = vals[e];
    float4 bb = *reinterpret_cast<const float4*>(b + (size_t)c * D_DIM + q * 4);
    float* o = out + (size_t)r * D_DIM + q * 4;
    atomicAdd(o + 0, v * bb.x);
    atomicAdd(o + 1, v * bb.y);
    atomicAdd(o + 2, v * bb.z);
    atomicAdd(o + 3, v * bb.w);
}

extern "C" void kernel_launch(void* const* d_in, const int* in_sizes, int n_in,
                              void* d_out, int out_size, void* d_ws, size_t ws_size,
                              hipStream_t stream) {
    const int*   idx  = (const int*)d_in[0];   // [2, E] flat int32
    const float* vals = (const float*)d_in[1]; // [E]
    const float* b    = (const float*)d_in[3]; // [N, 128]
    float*       out  = (float*)d_out;

    const int E = in_sizes[1];
    const int N = in_sizes[3] / D_DIM;
    const int* rows = idx;
    const int* cols = idx + E;

    // ws: rowcnt[8N] | spill_cnt[1] | pad64 | spill[SPILL_CAP] int2
    //     | slots[8*N*CSX] uint (64B-aligned) | b16[N*128] ushort
    size_t spill_off = (((size_t)(8 * (size_t)N + 1) * sizeof(int)) + 63) & ~(size_t)63;
    size_t slots_off = (spill_off + (size_t)SPILL_CAP * sizeof(int2) + 63) & ~(size_t)63;
    size_t b16_off   = slots_off + 8 * (size_t)N * CSX * sizeof(uint);
    size_t need      = b16_off + (size_t)N * D_DIM * sizeof(ushort);

    if (ws_size >= need && N <= 65536) {
        char*   ws        = (char*)d_ws;
        int*    rowcnt    = (int*)ws;
        int*    spill_cnt = rowcnt + 8 * (size_t)N;
        int2*   spill     = (int2*)(ws + spill_off);
        uint*   slots     = (uint*)(ws + slots_off);
        ushort* b16       = (ushort*)(ws + b16_off);

        (void)hipMemsetAsync(rowcnt, 0, (8 * (size_t)N + 1) * sizeof(int), stream);
        const int SB = (int)((E + 1023) / 1024);
        cvt_scatter<<<SB + CVTB, 256, 0, stream>>>(rows, cols, vals, b, b16,
                                                   N * D_DIM / 8, rowcnt,
                                                   spill_cnt, spill, slots,
                                                   E, N, SB);
        reduce_x<<<(N + 3) / 4, 256, 0, stream>>>(rowcnt, slots, b16, out, N);
        spill_apply<<<64, 256, 0, stream>>>(spill, spill_cnt, b, out);
    } else {
        size_t n4 = (size_t)N * D_DIM / 4;
        zero_kernel<<<2048, 256, 0, stream>>>(out, n4);
        long long total = (long long)E * 32;
        int ab = (int)((total + 255) / 256);
        atomic_spmm_kernel<<<ab, 256, 0, stream>>>(rows, cols, vals, b, out, E);
    }
}